// Round 5
// baseline (742.056 us; speedup 1.0000x reference)
//
#include <hip/hip_runtime.h>
#include <hip/hip_bf16.h>
#include <math.h>

typedef unsigned short u16;
typedef unsigned int u32;
typedef unsigned long long u64;
typedef signed char i8;

constexpr int NB = 64, NS = 128, NDM = 1024, NH = 16, NDK = 64;
constexpr int NM = NB * NS;  // 8192
constexpr float QEPS = 1e-8f;

typedef __attribute__((ext_vector_type(8))) short short8;
typedef __attribute__((ext_vector_type(4))) float f32x4;
typedef __attribute__((ext_vector_type(4))) int i32x4;

__device__ __forceinline__ u32 fenc(float f) {
  u32 u = __float_as_uint(f);
  return (u & 0x80000000u) ? ~u : (u | 0x80000000u);
}
__device__ __forceinline__ float fdec(u32 u) {
  u = (u & 0x80000000u) ? (u & 0x7FFFFFFFu) : ~u;
  return __uint_as_float(u);
}
// quantized values are small integers -> exact bf16 truncation
__device__ __forceinline__ u16 f2bf(float f) { return (u16)(__float_as_uint(f) >> 16); }
__device__ __forceinline__ float bf2f(u16 u) { return __uint_as_float(((u32)u) << 16); }

// async global->LDS, 16B/lane; lds dest = wave-uniform base + lane*16
__device__ __forceinline__ void glds16(const void* g, void* l) {
  __builtin_amdgcn_global_load_lds(
      (const __attribute__((address_space(1))) void*)(unsigned long long)(uintptr_t)g,
      (__attribute__((address_space(3))) void*)(u32)(uintptr_t)l, 16, 0, 0);
}

// gfx9 waitcnt imm: vmcnt[3:0]|exp[6:4]|lgkm[11:8]|vmcnt[5:4]<<14 (exp/lgkm = no-wait)
constexpr int WCNT(int vm) { return (vm & 15) | ((vm >> 4) << 14) | (7 << 4) | (15 << 8); }

// ---- scale slots ----
// [0..2] enc max(q,k,v)  [3..6] enc absmax(W*)  [7] enc max(x)
// [8..135] absmax_q per s; [136..263] absmax_k; [264..391] absmax_v (float bits)
// [392..519] colmax_p per j (float bits)

// init scl (block 0) + mask[B,S,S] int32 -> bitmask [B*S][2] u64
__global__ void initmask_kernel(const int* __restrict__ mask, u64* __restrict__ mb,
                                u32* __restrict__ scl) {
  if (blockIdx.x == 0)
    for (int i = threadIdx.x; i < 2048; i += 256) scl[i] = 0u;
  int row = blockIdx.x * 4 + (threadIdx.x >> 6);
  int lane = threadIdx.x & 63;
  const int* mrow = mask + (size_t)row * NS;
  u64 b0 = __ballot(mrow[lane] != 0);
  u64 b1 = __ballot(mrow[64 + lane] != 0);
  if (lane == 0) { mb[row * 2] = b0; mb[row * 2 + 1] = b1; }
}

// fused 7-way max reduce: y=0..2 max(q,k,v); y=3..6 absmax(Wq..Wo)
__global__ void fused_max_kernel(const float* __restrict__ q, const float* __restrict__ k,
                                 const float* __restrict__ v, const float* __restrict__ w0,
                                 const float* __restrict__ w1, const float* __restrict__ w2,
                                 const float* __restrict__ w3, u32* __restrict__ sclu) {
  int y = blockIdx.y;
  const float* src; size_t n4; int ab;
  switch (y) {
    case 0: src = q; n4 = (size_t)NM * NDM / 4; ab = 0; break;
    case 1: src = k; n4 = (size_t)NM * NDM / 4; ab = 0; break;
    case 2: src = v; n4 = (size_t)NM * NDM / 4; ab = 0; break;
    case 3: src = w0; n4 = (size_t)NDM * NDM / 4; ab = 1; break;
    case 4: src = w1; n4 = (size_t)NDM * NDM / 4; ab = 1; break;
    case 5: src = w2; n4 = (size_t)NDM * NDM / 4; ab = 1; break;
    default: src = w3; n4 = (size_t)NDM * NDM / 4; ab = 1; break;
  }
  float m = -INFINITY;
  size_t stride = (size_t)gridDim.x * blockDim.x;
  for (size_t i = (size_t)blockIdx.x * blockDim.x + threadIdx.x; i < n4; i += stride) {
    float4 f = ((const float4*)src)[i];
    if (ab) { f.x = fabsf(f.x); f.y = fabsf(f.y); f.z = fabsf(f.z); f.w = fabsf(f.w); }
    m = fmaxf(m, fmaxf(fmaxf(f.x, f.y), fmaxf(f.z, f.w)));
  }
  for (int off = 32; off; off >>= 1) m = fmaxf(m, __shfl_down(m, off));
  __shared__ float sm[4];
  if ((threadIdx.x & 63) == 0) sm[threadIdx.x >> 6] = m;
  __syncthreads();
  if (threadIdx.x == 0) {
    float r = fmaxf(fmaxf(sm[0], sm[1]), fmaxf(sm[2], sm[3]));
    atomicMax(&sclu[y], fenc(r));
  }
}

// weight quant -> i8 (-127..127) + per-output-channel column sums
__global__ __launch_bounds__(256)
void quant_w_i8_kernel(const float* __restrict__ w0, const float* __restrict__ w1,
                       const float* __restrict__ w2, const float* __restrict__ w3,
                       i8* __restrict__ dst, int* __restrict__ colsum,
                       const u32* __restrict__ sclu) {
  int y = blockIdx.y, row = blockIdx.x, tid = threadIdx.x;
  const float* src = (y == 0 ? w0 : y == 1 ? w1 : y == 2 ? w2 : w3) + (size_t)row * NDM;
  float s = fmaxf(fdec(sclu[3 + y]), QEPS) / 127.0f;
  float4 f = ((const float4*)src)[tid];
  int a = (int)fminf(fmaxf(rintf(f.x / s), -127.f), 127.f);
  int b = (int)fminf(fmaxf(rintf(f.y / s), -127.f), 127.f);
  int c = (int)fminf(fmaxf(rintf(f.z / s), -127.f), 127.f);
  int d = (int)fminf(fmaxf(rintf(f.w / s), -127.f), 127.f);
  ((int*)(dst + (size_t)y * NDM * NDM + (size_t)row * NDM))[tid] =
      (a & 255) | ((b & 255) << 8) | ((c & 255) << 16) | ((d & 255) << 24);
  int ssum = a + b + c + d;
  for (int off = 32; off; off >>= 1) ssum += __shfl_down(ssum, off);
  __shared__ int sm[4];
  if ((tid & 63) == 0) sm[tid >> 6] = ssum;
  __syncthreads();
  if (tid == 0) colsum[y * NDM + row] = sm[0] + sm[1] + sm[2] + sm[3];
}

// uint8 activation fake-quant -> shifted i8 (q-128)
__global__ void quant_a_kernel(const float* __restrict__ s0, const float* __restrict__ s1,
                               const float* __restrict__ s2, i8* __restrict__ dst,
                               const u32* __restrict__ sclu, int slot_base) {
  int y = blockIdx.y;
  const float* src = y == 0 ? s0 : y == 1 ? s1 : s2;
  i8* d = dst + (size_t)y * NM * NDM;
  float s = fmaxf(fdec(sclu[slot_base + y]), QEPS) / 255.0f;
  size_t n4 = (size_t)NM * NDM / 4;
  size_t stride = (size_t)gridDim.x * blockDim.x;
  for (size_t i = (size_t)blockIdx.x * blockDim.x + threadIdx.x; i < n4; i += stride) {
    float4 f = ((const float4*)src)[i];
    int a = (int)fminf(fmaxf(rintf(f.x / s), 0.f), 255.f) - 128;
    int b = (int)fminf(fmaxf(rintf(f.y / s), 0.f), 255.f) - 128;
    int c = (int)fminf(fmaxf(rintf(f.z / s), 0.f), 255.f) - 128;
    int e = (int)fminf(fmaxf(rintf(f.w / s), 0.f), 255.f) - 128;
    ((int*)d)[i] = (a & 255) | ((b & 255) << 8) | ((c & 255) << 16) | ((e & 255) << 24);
  }
}

// ------- GEMM: barrier-free per-wave pipeline, i8 MFMA, 3-deep LDS ring -------
// 1 wave/block, 64x64 tile, K=1024 in 16 steps of 64. No __syncthreads anywhere:
// each wave stages its own A/B strips via global_load_lds and waits with manual
// s_waitcnt vmcnt(16/8/0) (per-wave vmcnt is in-order; tile = 8 loads).
constexpr int GBK = 64, NITER = NDM / GBK;

template <bool PROJ>
__global__ __launch_bounds__(64)
void gemm_kernel(const i8* __restrict__ Abase, const i8* __restrict__ Wbase,
                 const int* __restrict__ colsum, const float* __restrict__ b0,
                 const float* __restrict__ b1, const float* __restrict__ b2,
                 float* __restrict__ Cbase, u32* __restrict__ sclu) {
  // XCD-swizzled decode: 16 bn-blocks sharing an A strip land on one XCD
  int id = blockIdx.x;
  int xcd = id & 7, s = id >> 3;
  int z = PROJ ? (s >> 8) : 0;
  int r = PROJ ? (s & 255) : s;
  int bm = ((r >> 4) * 8 + xcd) * 64;
  int wn = (r & 15) * 64;

  const i8* A = Abase + (size_t)z * NM * NDM + (size_t)bm * NDM;
  const i8* W = Wbase + (PROJ ? (size_t)z * NDM * NDM : 0) + (size_t)wn * NDM;
  float* C = Cbase + (PROJ ? (size_t)z * NM * NDM : 0);
  const float* bias = PROJ ? (z == 0 ? b0 : z == 1 ? b1 : b2) : b0;
  const int* cs = colsum + (PROJ ? z : 3) * NDM;

  __shared__ __align__(16) i8 Ab[3][64 * GBK];  // 3 x 4 KB
  __shared__ __align__(16) i8 Bb[3][64 * GBK];  // 3 x 4 KB

  const int lane = threadIdx.x;
  const int r16 = lane & 15, quad = lane >> 4;
  const int lrow = lane >> 2, lcol = (lane & 3) * 16;

  auto stage = [&](int k, int buf) {
#pragma unroll
    for (int p = 0; p < 4; p++) {
      glds16(A + (size_t)(p * 16 + lrow) * NDM + k * GBK + lcol, &Ab[buf][p * 1024]);
      glds16(W + (size_t)(p * 16 + lrow) * NDM + k * GBK + lcol, &Bb[buf][p * 1024]);
    }
  };
  stage(0, 0);
  stage(1, 1);

  i32x4 acc[4][4] = {};
  int bufr = 0, bufc = 2;
  for (int k = 0; k < NITER; k++) {
    if (k + 2 < NITER) stage(k + 2, bufc);
    // tile k fully landed when <= 2 tiles (16 loads) remain outstanding
    if (k < NITER - 2)      __builtin_amdgcn_s_waitcnt(WCNT(16));
    else if (k == NITER - 2) __builtin_amdgcn_s_waitcnt(WCNT(8));
    else                     __builtin_amdgcn_s_waitcnt(WCNT(0));
    const i8* ab = &Ab[bufr][0];
    const i8* bb = &Bb[bufr][0];
    i32x4 af[4], bf[4];
#pragma unroll
    for (int t = 0; t < 4; t++) {
      af[t] = *(const i32x4*)(ab + (t * 16 + r16) * GBK + quad * 16);
      bf[t] = *(const i32x4*)(bb + (t * 16 + r16) * GBK + quad * 16);
    }
#pragma unroll
    for (int i = 0; i < 4; i++)
#pragma unroll
      for (int j = 0; j < 4; j++)
        acc[i][j] = __builtin_amdgcn_mfma_i32_16x16x64_i8(af[i], bf[j], acc[i][j], 0, 0, 0);
    bufr = bufr == 2 ? 0 : bufr + 1;
    bufc = bufc == 2 ? 0 : bufc + 1;
  }

  float s_in = fmaxf(fdec(sclu[PROJ ? z : 7]), QEPS) / 255.0f;
  float s_w = fmaxf(fdec(sclu[PROJ ? 3 + z : 6]), QEPS) / 127.0f;
  float sc = s_in * s_w;

  float bq[4];
  int csj[4];
#pragma unroll
  for (int j = 0; j < 4; j++) {
    int gc = wn + j * 16 + r16;
    bq[j] = rintf(bias[gc] / sc) * sc;
    csj[j] = cs[gc] * 128;  // undo the x-128 input shift
  }
#pragma unroll
  for (int i = 0; i < 4; i++) {
#pragma unroll
    for (int rr = 0; rr < 4; rr++) {
      int row = bm + i * 16 + quad * 4 + rr;
      float rm = 0.0f;
#pragma unroll
      for (int j = 0; j < 4; j++) {
        int gc = wn + j * 16 + r16;
        float val = (float)(acc[i][j][rr] + csj[j]) * sc + bq[j];
        C[(size_t)row * NDM + gc] = val;
        if (PROJ) rm = fmaxf(rm, fabsf(val));
      }
      if (PROJ) {
#pragma unroll
        for (int off = 1; off < 16; off <<= 1) rm = fmaxf(rm, __shfl_xor(rm, off));
        if (r16 == 0)
          atomicMax((int*)&sclu[8 + z * 128 + (row & 127)], __float_as_int(rm));
      }
    }
  }
}

// ---------------- attention (quantization fused into staging) ----------------
__global__ __launch_bounds__(256)
void attn_scores_kernel(const float* __restrict__ proj, const u64* __restrict__ mb,
                        const float* __restrict__ scl, u32* __restrict__ sclu,
                        float* __restrict__ Pn) {
  const int bh = blockIdx.x, b = bh >> 4, h = bh & 15;
  const int tid = threadIdx.x, lane = tid & 63, wave = tid >> 6;
  const int r16 = lane & 15, quad = lane >> 4;

  __shared__ __align__(16) i8 Qs[NS][80];
  __shared__ __align__(16) i8 Ks[NS][80];
  __shared__ float sqv[NS], skv[NS];
  __shared__ float cmw[4][NS];

  {  // stage + quantize q,k from fp32 proj (each element consumed by exactly this block)
    int row = tid >> 1, hf = (tid & 1) * 32;
    float sq = fmaxf(scl[8 + row], QEPS) / 127.0f;
    float sk = fmaxf(scl[8 + 128 + row], QEPS) / 127.0f;
    const float* qp = proj + ((size_t)b * NS + row) * NDM + h * NDK + hf;
    const float* kp = proj + (size_t)NM * NDM + ((size_t)b * NS + row) * NDM + h * NDK + hf;
    int qw[8], kw[8];
#pragma unroll
    for (int c = 0; c < 8; c++) {
      float4 qf = *(const float4*)(qp + c * 4);
      float4 kf = *(const float4*)(kp + c * 4);
      int q0 = (int)fminf(fmaxf(rintf(qf.x / sq), -128.f), 127.f);
      int q1 = (int)fminf(fmaxf(rintf(qf.y / sq), -128.f), 127.f);
      int q2 = (int)fminf(fmaxf(rintf(qf.z / sq), -128.f), 127.f);
      int q3 = (int)fminf(fmaxf(rintf(qf.w / sq), -128.f), 127.f);
      qw[c] = (q0 & 255) | ((q1 & 255) << 8) | ((q2 & 255) << 16) | ((q3 & 255) << 24);
      int k0 = (int)fminf(fmaxf(rintf(kf.x / sk), -128.f), 127.f);
      int k1 = (int)fminf(fmaxf(rintf(kf.y / sk), -128.f), 127.f);
      int k2 = (int)fminf(fmaxf(rintf(kf.z / sk), -128.f), 127.f);
      int k3 = (int)fminf(fmaxf(rintf(kf.w / sk), -128.f), 127.f);
      kw[c] = (k0 & 255) | ((k1 & 255) << 8) | ((k2 & 255) << 16) | ((k3 & 255) << 24);
    }
    *(int4*)&Qs[row][hf] = *(int4*)&qw[0];
    *(int4*)&Qs[row][hf + 16] = *(int4*)&qw[4];
    *(int4*)&Ks[row][hf] = *(int4*)&kw[0];
    *(int4*)&Ks[row][hf + 16] = *(int4*)&kw[4];
    if (tid < NS) {
      sqv[tid] = fmaxf(scl[8 + tid], QEPS) / 127.0f;
      skv[tid] = fmaxf(scl[8 + 128 + tid], QEPS) / 127.0f;
    }
  }
  __syncthreads();

  const int rowbase = wave * 32;
  i32x4 acc[2][8] = {};
#pragma unroll
  for (int mt = 0; mt < 2; mt++) {
    i32x4 a = *(const i32x4*)&Qs[rowbase + mt * 16 + r16][quad * 16];
#pragma unroll
    for (int nt = 0; nt < 8; nt++) {
      i32x4 bfrag = *(const i32x4*)&Ks[nt * 16 + r16][quad * 16];
      acc[mt][nt] = __builtin_amdgcn_mfma_i32_16x16x64_i8(a, bfrag, acc[mt][nt], 0, 0, 0);
    }
  }

  float skc[8], cm[8];
#pragma unroll
  for (int nt = 0; nt < 8; nt++) { skc[nt] = skv[nt * 16 + r16]; cm[nt] = 0.0f; }

#pragma unroll
  for (int mt = 0; mt < 2; mt++) {
#pragma unroll
    for (int rr = 0; rr < 4; rr++) {
      int row = rowbase + mt * 16 + quad * 4 + rr;
      float sq = sqv[row];
      const u64* mrow = mb + ((size_t)b * NS + row) * 2;
      u64 m0 = mrow[0], m1 = mrow[1];
      float vals[8];
      float mx = -INFINITY;
#pragma unroll
      for (int nt = 0; nt < 8; nt++) {
        float v = (float)acc[mt][nt][rr] * (sq * skc[nt]) * 0.125f;
        u64 bits = nt < 4 ? m0 : m1;
        if (((bits >> ((nt * 16 + r16) & 63)) & 1ull) == 0) v = -1e9f;
        vals[nt] = v;
        mx = fmaxf(mx, v);
      }
#pragma unroll
      for (int off = 1; off < 16; off <<= 1) mx = fmaxf(mx, __shfl_xor(mx, off));
      float sum = 0.0f;
#pragma unroll
      for (int nt = 0; nt < 8; nt++) { vals[nt] = __expf(vals[nt] - mx); sum += vals[nt]; }
#pragma unroll
      for (int off = 1; off < 16; off <<= 1) sum += __shfl_xor(sum, off);
      float* prow = Pn + ((size_t)bh * NS + row) * NS;
#pragma unroll
      for (int nt = 0; nt < 8; nt++) {
        float p = vals[nt] / sum;
        prow[nt * 16 + r16] = p;
        cm[nt] = fmaxf(cm[nt], p);
      }
    }
  }

#pragma unroll
  for (int nt = 0; nt < 8; nt++) {
    float c = cm[nt];
    c = fmaxf(c, __shfl_xor(c, 16));
    c = fmaxf(c, __shfl_xor(c, 32));
    if (quad == 0) cmw[wave][nt * 16 + r16] = c;
  }
  __syncthreads();
  if (tid < NS) {
    float c = fmaxf(fmaxf(cmw[0][tid], cmw[1][tid]), fmaxf(cmw[2][tid], cmw[3][tid]));
    atomicMax((int*)&sclu[392 + tid], __float_as_int(c));  // p >= 0
  }
}

__global__ __launch_bounds__(256)
void attn_pv_kernel(const float* __restrict__ Pn, const float* __restrict__ projv,
                    const float* __restrict__ scl, float* __restrict__ xout,
                    u32* __restrict__ xmax_slot) {
  const int bh = blockIdx.x, b = bh >> 4, h = bh & 15;
  const int tid = threadIdx.x, lane = tid & 63, wave = tid >> 6;
  const int r16 = lane & 15, quad = lane >> 4;
  const int rowbase = wave * 32;

  __shared__ __align__(16) u16 Ps[NS][72];
  __shared__ __align__(16) u16 Vhi[64][72];
  __shared__ __align__(16) u16 Vlo[64][72];
  __shared__ float spv[NS], svv[NS];

  if (tid < NS) {
    spv[tid] = fmaxf(scl[392 + tid], QEPS) / 127.0f;
    svv[tid] = fmaxf(scl[8 + 256 + tid], QEPS) / 127.0f;
  }

  f32x4 xacc[2][4] = {};
  for (int half = 0; half < 2; half++) {
    __syncthreads();
    {  // quantize P half with colmax scales -> bf16-exact ints in LDS
      int row = tid >> 1, jl0 = (tid & 1) * 32;
      const float* prow = Pn + ((size_t)bh * NS + row) * NS + half * 64 + jl0;
#pragma unroll
      for (int c4 = 0; c4 < 8; c4++) {
        float4 p = *(const float4*)(prow + c4 * 4);
        int j = half * 64 + jl0 + c4 * 4;
        ushort4 o;
        o.x = f2bf(fminf(fmaxf(rintf(p.x / spv[j + 0]), -128.f), 127.f));
        o.y = f2bf(fminf(fmaxf(rintf(p.y / spv[j + 1]), -128.f), 127.f));
        o.z = f2bf(fminf(fmaxf(rintf(p.z / spv[j + 2]), -128.f), 127.f));
        o.w = f2bf(fminf(fmaxf(rintf(p.w / spv[j + 3]), -128.f), 127.f));
        *(ushort4*)&Ps[row][jl0 + c4 * 4] = o;
      }
    }
    {  // stage V half from fp32 proj: quantize, fold per-j scale via hi/lo bf16 split
      int jl = tid >> 2, d0 = (tid & 3) * 16;
      int j = half * 64 + jl;
      float sv = svv[j];
      float g = spv[j] * sv;
      const float* vp = projv + ((size_t)b * NS + j) * NDM + h * NDK + d0;
#pragma unroll
      for (int c = 0; c < 4; c++) {
        float4 vf = *(const float4*)(vp + c * 4);
        float vq[4];
        vq[0] = fminf(fmaxf(rintf(vf.x / sv), -128.f), 127.f);
        vq[1] = fminf(fmaxf(rintf(vf.y / sv), -128.f), 127.f);
        vq[2] = fminf(fmaxf(rintf(vf.z / sv), -128.f), 127.f);
        vq[3] = fminf(fmaxf(rintf(vf.w / sv), -128.f), 127.f);
#pragma unroll
        for (int t = 0; t < 4; t++) {
          float w = vq[t] * g;
          u16 hi = f2bf(w);
          Vhi[d0 + c * 4 + t][jl] = hi;
          Vlo[d0 + c * 4 + t][jl] = f2bf(w - bf2f(hi));
        }
      }
    }
    __syncthreads();
#pragma unroll
    for (int kk = 0; kk < 2; kk++) {
      short8 pa[2];
#pragma unroll
      for (int mt = 0; mt < 2; mt++)
        pa[mt] = *(const short8*)&Ps[rowbase + mt * 16 + r16][kk * 32 + quad * 8];
#pragma unroll
      for (int nt = 0; nt < 4; nt++) {
        short8 vh = *(const short8*)&Vhi[nt * 16 + r16][kk * 32 + quad * 8];
        short8 vl = *(const short8*)&Vlo[nt * 16 + r16][kk * 32 + quad * 8];
#pragma unroll
        for (int mt = 0; mt < 2; mt++) {
          xacc[mt][nt] = __builtin_amdgcn_mfma_f32_16x16x32_bf16(pa[mt], vh, xacc[mt][nt], 0, 0, 0);
          xacc[mt][nt] = __builtin_amdgcn_mfma_f32_16x16x32_bf16(pa[mt], vl, xacc[mt][nt], 0, 0, 0);
        }
      }
    }
  }

  float mx = -INFINITY;
#pragma unroll
  for (int mt = 0; mt < 2; mt++)
#pragma unroll
    for (int nt = 0; nt < 4; nt++)
#pragma unroll
      for (int rr = 0; rr < 4; rr++) {
        int row = rowbase + mt * 16 + quad * 4 + rr;
        xout[((size_t)b * NS + row) * NDM + h * NDK + nt * 16 + r16] = xacc[mt][nt][rr];
        mx = fmaxf(mx, xacc[mt][nt][rr]);
      }
#pragma unroll
  for (int off = 1; off < 64; off <<= 1) mx = fmaxf(mx, __shfl_xor(mx, off));
  if (lane == 0) atomicMax(xmax_slot, fenc(mx));
}

// ---------------- workspace layout (total ~188.2 MiB) ----------------
constexpr size_t OFF_SCL = 0;                                  // 8 KB
constexpr size_t OFF_CS  = 8192;                               // 16 KB
constexpr size_t OFF_MB  = OFF_CS + 4 * NDM * 4;               // 128 KB
constexpr size_t OFF_W   = OFF_MB + (size_t)NM * 16;           // 4 MiB i8 weights
constexpr size_t OFF_XQ  = OFF_W + 4 * (size_t)NDM * NDM;      // 24 MiB i8 acts
constexpr size_t OFF_PQ  = OFF_XQ + 3 * (size_t)NM * NDM;      // 96 MiB f32 proj
constexpr size_t OFF_PN  = OFF_PQ + 3 * (size_t)NM * NDM * 4;  // 64 MiB f32 Pn
// xout aliases projv (block-private slices: reads precede writes within each block)

extern "C" void kernel_launch(void* const* d_in, const int* in_sizes, int n_in,
                              void* d_out, int out_size, void* d_ws, size_t ws_size,
                              hipStream_t stream) {
  const float* query = (const float*)d_in[0];
  const float* key = (const float*)d_in[1];
  const float* value = (const float*)d_in[2];
  const int* mask = (const int*)d_in[3];
  const float* Wq = (const float*)d_in[4]; const float* bq = (const float*)d_in[5];
  const float* Wk = (const float*)d_in[6]; const float* bk = (const float*)d_in[7];
  const float* Wv = (const float*)d_in[8]; const float* bv = (const float*)d_in[9];
  const float* Wo = (const float*)d_in[10]; const float* bo = (const float*)d_in[11];

  char* ws = (char*)d_ws;
  float* scl = (float*)(ws + OFF_SCL);
  u32* sclu = (u32*)scl;
  int* colsum = (int*)(ws + OFF_CS);
  u64* mb = (u64*)(ws + OFF_MB);
  i8* wb = (i8*)(ws + OFF_W);
  i8* wob = wb + 3 * (size_t)NDM * NDM;
  i8* xq = (i8*)(ws + OFF_XQ);
  float* proj = (float*)(ws + OFF_PQ);
  float* Pn = (float*)(ws + OFF_PN);
  float* projv = proj + 2 * (size_t)NM * NDM;
  float* xout = projv;

  initmask_kernel<<<NM / 4, 256, 0, stream>>>(mask, mb, sclu);
  fused_max_kernel<<<dim3(512, 7), 256, 0, stream>>>(query, key, value, Wq, Wk, Wv, Wo, sclu);
  quant_w_i8_kernel<<<dim3(NDM, 4), 256, 0, stream>>>(Wq, Wk, Wv, Wo, wb, colsum, sclu);
  quant_a_kernel<<<dim3(1024, 3), 256, 0, stream>>>(query, key, value, xq, sclu, 0);

  gemm_kernel<true><<<6144, 64, 0, stream>>>(xq, wb, colsum, bq, bk, bv, proj, sclu);

  attn_scores_kernel<<<NB * NH, 256, 0, stream>>>(proj, mb, scl, sclu, Pn);
  attn_pv_kernel<<<NB * NH, 256, 0, stream>>>(Pn, projv, scl, xout, sclu + 7);

  quant_a_kernel<<<dim3(1024, 1), 256, 0, stream>>>(xout, xout, xout, xq, sclu, 7);
  gemm_kernel<false><<<2048, 64, 0, stream>>>(xq, wob, colsum, bo, bo, bo,
                                              (float*)d_out, sclu);
}